// Round 15
// baseline (3835.458 us; speedup 1.0000x reference)
//
#include <hip/hip_runtime.h>

typedef _Float16 h8 __attribute__((ext_vector_type(8)));
typedef float f32x4 __attribute__((ext_vector_type(4)));
typedef int  i4 __attribute__((ext_vector_type(4)));

#define NTHREADS 1024
#define ROWS 16
#define NBLK 256   // 4096 tokens / 16 rows

// LDS layout (bytes), total = 160 KiB:
//   buf8A : 16x1024 int8 swizzled @      0 (16384)
//   buf8B : 16x1024 int8 swizzled @  16384 (16384)
//           Yh fp16 16x128 swz    @  16384 ( 4096)  (alias; dead while buf8B live)
//           red i4[512]           @  24576 ( 8192)  (alias; L3 reduce)
//   ring  : 16 waves x 2 slots x 4096 @ 32768 (131072)  async W staging
#define SMEM_BYTES 163840

#define GLOAD16(gp, lp) __builtin_amdgcn_global_load_lds( \
    (const __attribute__((address_space(1))) void*)(gp),  \
    (__attribute__((address_space(3))) void*)(lp), 16, 0, 0)

__device__ __forceinline__ float fast_tanh(float x) {
    float e = __expf(2.0f * x);
    return 1.0f - 2.0f / (e + 1.0f);
}

// flush LDS + block barrier WITHOUT draining vmcnt (keeps async prefetch alive)
__device__ __forceinline__ void lightbar() {
    asm volatile("s_waitcnt lgkmcnt(0)" ::: "memory");
    __builtin_amdgcn_sched_barrier(0);
    __builtin_amdgcn_s_barrier();
    __builtin_amdgcn_sched_barrier(0);
}

// ---------------- weight pack kernels ----------------
template<int K>
__global__ void __launch_bounds__(256) pack_kernel(const float* __restrict__ src,
                                                   _Float16* __restrict__ dst, int nfrag) {
    constexpr int NK = K / 32;
    int idx = blockIdx.x * 256 + threadIdx.x;
    if (idx >= nfrag) return;
    int lane = idx & 63;
    int ct   = (idx >> 6) & 3;
    int kk   = (idx >> 8) % NK;
    int w    = idx / (256 * NK);
    int col  = w * 64 + ct * 16 + (lane & 15);
    int kb   = kk * 32 + (lane >> 4) * 8;
    const float* s = src + (size_t)col * K + kb;
    f32x4 v0 = *(const f32x4*)s;
    f32x4 v1 = *(const f32x4*)(s + 4);
    h8 h;
    h[0]=(_Float16)v0[0]; h[1]=(_Float16)v0[1]; h[2]=(_Float16)v0[2]; h[3]=(_Float16)v0[3];
    h[4]=(_Float16)v1[0]; h[5]=(_Float16)v1[1]; h[6]=(_Float16)v1[2]; h[7]=(_Float16)v1[3];
    *(h8*)(dst + (size_t)idx * 8) = h;
}

__global__ void __launch_bounds__(256) pack8_kernel(const float* __restrict__ src,
                                                    char* __restrict__ dst, int nfrag) {
    int idx = blockIdx.x * 256 + threadIdx.x;
    if (idx >= nfrag) return;
    int lane = idx & 63;
    int ct   = (idx >> 6) & 3;
    int kk   = (idx >> 8) & 15;
    int w    = idx >> 12;
    int col  = w * 64 + ct * 16 + (lane & 15);
    int kb   = kk * 64 + (lane >> 4) * 16;
    const float* s = src + (size_t)col * 1024 + kb;
    union { char q[16]; i4 v; } u;
#pragma unroll
    for (int j = 0; j < 16; ++j)
        u.q[j] = (char)__float2int_rn(s[j] * 4064.0f);   // 32*127
    *(i4*)(dst + (size_t)idx * 16) = u.v;
}

__global__ void __launch_bounds__(256) pack3q_kernel(const float* __restrict__ src,
                                                     char* __restrict__ dst, int nfrag) {
    int idx = blockIdx.x * 256 + threadIdx.x;
    if (idx >= nfrag) return;
    int lane = idx & 63;
    int kk   = (idx >> 6) & 15;
    int cg   = idx >> 10;
    int col  = cg * 16 + (lane & 15);
    int kb   = kk * 64 + (lane >> 4) * 16;
    const float* s = src + (size_t)col * 1024 + kb;
    union { char q[16]; i4 v; } u;
#pragma unroll
    for (int j = 0; j < 16; ++j)
        u.q[j] = (char)__float2int_rn(s[j] * 4064.0f);
    *(i4*)(dst + (size_t)idx * 16) = u.v;
}

// ---------------- layer 0: fp16 x fp16 (K=128), reg ping-pong ----------------
__device__ __forceinline__ void mlp0(const char* __restrict__ src, char* __restrict__ dst,
                                     const _Float16* __restrict__ Wp, f32x4 bv,
                                     int w, int l15, int lhi, int lane)
{
    constexpr int NK = 4;
    const int colbase = w * 64;
    const _Float16* wb = Wp + (size_t)w * NK * 2048 + lane * 8;

    f32x4 acc[4];
#pragma unroll
    for (int ct = 0; ct < 4; ++ct) {
        f32x4 a; a[0] = bv[ct]; a[1] = bv[ct]; a[2] = bv[ct]; a[3] = bv[ct];
        acc[ct] = a;
    }

    h8 bE[4], bO[4], aE, aO;
    auto loadB = [&](h8* b, int kk) {
#pragma unroll
        for (int ct = 0; ct < 4; ++ct)
            b[ct] = *(const h8*)(wb + (size_t)kk * 2048 + ct * 512);
    };
    auto loadA = [&](h8& a, int kk) {
        int byte = (l15 * 256 + kk * 64 + lhi * 16) ^ ((l15 & 7) << 4);
        a = *(const h8*)(src + byte);
    };
    auto mfma4 = [&](h8& a, h8* b) {
        __builtin_amdgcn_s_setprio(1);
#pragma unroll
        for (int ct = 0; ct < 4; ++ct)
            acc[ct] = __builtin_amdgcn_mfma_f32_16x16x32_f16(a, b[ct], acc[ct], 0, 0, 0);
        __builtin_amdgcn_s_setprio(0);
    };

    loadB(bE, 0); loadA(aE, 0);
    loadB(bO, 1); loadA(aO, 1);
    mfma4(aE, bE);
    loadB(bE, 2); loadA(aE, 2);
    mfma4(aO, bO);
    loadB(bO, 3); loadA(aO, 3);
    mfma4(aE, bE);
    mfma4(aO, bO);

#pragma unroll
    for (int ct = 0; ct < 4; ++ct)
#pragma unroll
        for (int j = 0; j < 4; ++j) {
            int row = lhi * 4 + j;
            int gc = colbase + ct * 16 + l15;
            int q = __float2int_rn(fast_tanh(acc[ct][j]) * 127.0f);
            int byte = (row * 1024 + gc) ^ ((row & 7) << 4);
            *(char*)(dst + byte) = (char)q;
        }
}

// ---- async staging: issue chunks 0,1 (4 x 16B gload_lds each) into wave ring ----
__device__ __forceinline__ void stage2(const char* wbl, char* ringW)
{
#pragma unroll
    for (int c = 0; c < 2; ++c) {
        const char* g = wbl + (size_t)c * 4096;
        char* l = ringW + c * 4096;
#pragma unroll
        for (int ct = 0; ct < 4; ++ct)
            GLOAD16(g + ct * 1024, l + ct * 1024);
    }
}

// ------- layers 1/2: int8, B via vmcnt-counted LDS ring; A preloaded in registers -------
__device__ __forceinline__ void mlp8c(const char* __restrict__ src, char* __restrict__ dst,
                                      const char* wbl, char* ringW, const char* ringR,
                                      f32x4 bv, int w, int l15, int lhi,
                                      const char* nextwb)
{
    const int colbase = w * 64;
    i4 acc[4];
#pragma unroll
    for (int ct = 0; ct < 4; ++ct) { i4 z; z[0]=0; z[1]=0; z[2]=0; z[3]=0; acc[ct] = z; }

    // ---- preload all 16 A-fragments (256 B/lane) into registers; static indices ----
    i4 Areg[16];
#pragma unroll
    for (int kk = 0; kk < 16; ++kk) {
        int byte = (l15 * 1024 + kk * 64 + lhi * 16) ^ ((l15 & 7) << 4);
        Areg[kk] = *(const i4*)(src + byte);
    }
    asm volatile("s_waitcnt lgkmcnt(0)" ::: "memory");
    __builtin_amdgcn_sched_barrier(0);

    i4 B0, B1, B2, B3;
    auto readB = [&](int kk) {
        const char* sl = ringR + (kk & 1) * 4096;
        B0 = *(const i4*)(sl);
        B1 = *(const i4*)(sl + 1024);
        B2 = *(const i4*)(sl + 2048);
        B3 = *(const i4*)(sl + 3072);
    };
    auto mfma4 = [&](const i4& A) {
        __builtin_amdgcn_s_setprio(1);
        acc[0] = __builtin_amdgcn_mfma_i32_16x16x64_i8(A, B0, acc[0], 0, 0, 0);
        acc[1] = __builtin_amdgcn_mfma_i32_16x16x64_i8(A, B1, acc[1], 0, 0, 0);
        acc[2] = __builtin_amdgcn_mfma_i32_16x16x64_i8(A, B2, acc[2], 0, 0, 0);
        acc[3] = __builtin_amdgcn_mfma_i32_16x16x64_i8(A, B3, acc[3], 0, 0, 0);
        __builtin_amdgcn_s_setprio(0);
    };

    // fully unrolled chunk loop: static kk everywhere; ring state lives in vmcnt
#pragma unroll
    for (int kk = 0; kk < 15; ++kk) {
        asm volatile("s_waitcnt vmcnt(4)" ::: "memory");   // chunk kk landed
        __builtin_amdgcn_sched_barrier(0);
        readB(kk);
        asm volatile("s_waitcnt lgkmcnt(0)" ::: "memory"); // slot reads done before reuse
        __builtin_amdgcn_sched_barrier(0);
        if (kk < 14) {                                     // issue chunk kk+2 into slot kk&1
            const char* g = wbl + (size_t)(kk + 2) * 4096;
            char* l = ringW + (kk & 1) * 4096;
#pragma unroll
            for (int ct = 0; ct < 4; ++ct)
                GLOAD16(g + ct * 1024, l + ct * 1024);
        }
        __builtin_amdgcn_sched_barrier(0);
        mfma4(Areg[kk]);
    }
    asm volatile("s_waitcnt vmcnt(0)" ::: "memory");       // chunk 15 landed
    __builtin_amdgcn_sched_barrier(0);
    readB(15);
    asm volatile("s_waitcnt lgkmcnt(0)" ::: "memory");
    __builtin_amdgcn_sched_barrier(0);
    // ring fully drained: tail-issue next stage's chunks 0,1
    stage2(nextwb, ringW);
    __builtin_amdgcn_sched_barrier(0);
    mfma4(Areg[15]);

    const float DEQ = 1.0f / 516128.0f;   // 1/(32*127*127)
#pragma unroll
    for (int ct = 0; ct < 4; ++ct) {
        int gc = colbase + ct * 16 + l15;
#pragma unroll
        for (int j = 0; j < 4; ++j) {
            int row = lhi * 4 + j;
            float v = fast_tanh((float)acc[ct][j] * DEQ + bv[ct]);
            int q = __float2int_rn(v * 127.0f);
            int byte = (row * 1024 + gc) ^ ((row & 7) << 4);
            *(char*)(dst + byte) = (char)q;
        }
    }
}

__global__ void
__attribute__((amdgpu_flat_work_group_size(NTHREADS, NTHREADS)))
node_kernel(const float* __restrict__ y0,
            const float* __restrict__ tarr,
            const float* __restrict__ W_aug,
            const float* __restrict__ b_aug,
            const float* __restrict__ b0,
            const float* __restrict__ b1,
            const float* __restrict__ b2,
            const float* __restrict__ b3,
            const _Float16* __restrict__ W0p,
            const char* __restrict__ W1q,
            const char* __restrict__ W2q,
            const char* __restrict__ W3q,
            float* __restrict__ out)
{
    __shared__ __align__(16) char smem[SMEM_BYTES];
    char* buf8A = smem;
    char* buf8B = smem + 16384;
    char* Yh    = smem + 16384;            // alias buf8B[0:4096]
    i4*   red   = (i4*)(smem + 24576);     // alias buf8B[8192:16384]
    float* Yf   = (float*)smem;            // alias buf8A (init only)
    char* ring  = smem + 32768;

    const int tid  = threadIdx.x;
    const int lane = tid & 63;
    const int w    = tid >> 6;       // 0..15
    const int l15  = lane & 15;
    const int lhi  = lane >> 4;
    const int row0 = blockIdx.x * ROWS;

    const float dtv = tarr[1] - tarr[0];

    // ---- load y0 rows into Yf[:, 0:64] ----
    if (tid < 256) {
        int idx = tid * 4;
        int r = idx >> 6;
        int c = idx & 63;
        f32x4 v = *(const f32x4*)(y0 + (size_t)(row0 + r) * 64 + c);
        *(f32x4*)(Yf + r * 128 + c) = v;
    }
    __syncthreads();

    // ---- augment ----
    {
        int r = tid >> 6;
        int a0 = tid & 63;
        float acc = b_aug[a0];
        for (int d = 0; d < 64; ++d)
            acc += Yf[r * 128 + d] * W_aug[a0 * 64 + d];
        __syncthreads();
        Yf[r * 128 + 64 + a0] = acc;
    }
    __syncthreads();

    // thread-owned state (waves 0..7): col g = w*16+l15, rows lhi*4+j
    const int g = w * 16 + l15;
    f32x4 yreg;
    if (w < 8) {
#pragma unroll
        for (int j = 0; j < 4; ++j)
            yreg[j] = Yf[(lhi * 4 + j) * 128 + g];
    }
    h8 yh0;
    int yh0_byte;
    if (tid < 256) {
        int r = tid >> 4;
        int c = (tid & 15) * 8;
        const float* p = Yf + r * 128 + c;
#pragma unroll
        for (int j = 0; j < 8; ++j) yh0[j] = (_Float16)p[j];
        yh0_byte = ((r * 128 + c) * 2) ^ ((r & 7) << 4);
    }
    __syncthreads();
    if (tid < 256) *(h8*)(Yh + yh0_byte) = yh0;
    __syncthreads();

    // per-wave pointers
    const char* wb1 = W1q + (size_t)w * 65536 + lane * 16;
    const char* wb2 = W2q + (size_t)w * 65536 + lane * 16;
    char* ringW = ring + w * 8192;           // wave-uniform slot base
    const char* ringR = ringW + lane * 16;   // per-lane read base

    // biases in registers (keep vmcnt clean inside mlp8c)
    f32x4 b0v, b1v, b2v;
#pragma unroll
    for (int ct = 0; ct < 4; ++ct) {
        b0v[ct] = b0[w * 64 + ct * 16 + l15];
        b1v[ct] = b1[w * 64 + ct * 16 + l15];
        b2v[ct] = b2[w * 64 + ct * 16 + l15];
    }
    const int cg  = w & 7;
    const int kk0 = (w >> 3) * 8;
    const char* wb3 = W3q + (size_t)cg * 16384 + lane * 16;
    const float b3v = (w < 8) ? b3[g] : 0.0f;
    const float DEQ3 = 1.0f / 516128.0f;

    // prologue: stage L1 chunks 0,1 for step 0
    stage2(wb1, ringW);

    // ---- 31 Euler steps ----
    for (int s = 0; s < 31; ++s) {
        // L0: Yh -> buf8A (L1 chunks already in flight/landed)
        mlp0(Yh, buf8A, W0p, b0v, w, l15, lhi, lane);
        lightbar();

        // L1: buf8A -> buf8B; tail-issues L2 chunks 0,1
        mlp8c(buf8A, buf8B, wb1, ringW, ringR, b1v, w, l15, lhi, wb2);
        lightbar();

        // L2: buf8B -> buf8A; tail-issues NEXT STEP's L1 chunks 0,1
        mlp8c(buf8B, buf8A, wb2, ringW, ringR, b2v, w, l15, lhi, wb1);
        lightbar();

        // L3: DY[16][128] = buf8A @ W3q^T + b3 (int8, K split across wave halves)
        {
            i4 acc3; acc3[0]=0; acc3[1]=0; acc3[2]=0; acc3[3]=0;
            i4 c3E, c3O, x3E, x3O;
            auto loadB3 = [&](i4& b, int kk) {
                b = *(const i4*)(wb3 + (size_t)kk * 1024);
            };
            auto loadA3 = [&](i4& a, int kk) {
                int byte = (l15 * 1024 + kk * 64 + lhi * 16) ^ ((l15 & 7) << 4);
                a = *(const i4*)(buf8A + byte);
            };
            loadB3(c3E, kk0 + 0); loadA3(x3E, kk0 + 0);
#pragma unroll
            for (int q = 0; q < 3; ++q) {
                loadB3(c3O, kk0 + 2 * q + 1); loadA3(x3O, kk0 + 2 * q + 1);
                acc3 = __builtin_amdgcn_mfma_i32_16x16x64_i8(x3E, c3E, acc3, 0, 0, 0);
                loadB3(c3E, kk0 + 2 * q + 2); loadA3(x3E, kk0 + 2 * q + 2);
                acc3 = __builtin_amdgcn_mfma_i32_16x16x64_i8(x3O, c3O, acc3, 0, 0, 0);
            }
            loadB3(c3O, kk0 + 7); loadA3(x3O, kk0 + 7);
            acc3 = __builtin_amdgcn_mfma_i32_16x16x64_i8(x3E, c3E, acc3, 0, 0, 0);
            acc3 = __builtin_amdgcn_mfma_i32_16x16x64_i8(x3O, c3O, acc3, 0, 0, 0);

            if (w >= 8)
                red[cg * 64 + lane] = acc3;
            lightbar();
            if (w < 8) {
                i4 part = red[w * 64 + lane];
#pragma unroll
                for (int j = 0; j < 4; ++j) {
                    int row = lhi * 4 + j;
                    float dy = (float)(acc3[j] + part[j]) * DEQ3 + b3v;
                    float nv = yreg[j] + dtv * dy;
                    yreg[j] = nv;
                    int byte = ((row * 128 + g) * 2) ^ ((row & 7) << 4);
                    *(_Float16*)(Yh + byte) = (_Float16)nv;
                }
            }
        }
        lightbar();
    }

    // drain dangling prefetch (last step tail-issued L1 chunks we never consume)
    asm volatile("s_waitcnt vmcnt(0)" ::: "memory");

    // ---- output ----
    if (w < 4) {
#pragma unroll
        for (int j = 0; j < 4; ++j) {
            int row = lhi * 4 + j;
            out[(size_t)(row0 + row) * 64 + g] = yreg[j];
        }
    }
}

extern "C" void kernel_launch(void* const* d_in, const int* in_sizes, int n_in,
                              void* d_out, int out_size, void* d_ws, size_t ws_size,
                              hipStream_t stream)
{
    const float* y0    = (const float*)d_in[0];
    const float* tarr  = (const float*)d_in[1];
    const float* W_aug = (const float*)d_in[2];
    const float* b_aug = (const float*)d_in[3];
    const float* W0    = (const float*)d_in[4];
    const float* b0    = (const float*)d_in[5];
    const float* W1    = (const float*)d_in[6];
    const float* b1    = (const float*)d_in[7];
    const float* W2    = (const float*)d_in[8];
    const float* b2    = (const float*)d_in[9];
    const float* W3    = (const float*)d_in[10];
    const float* b3    = (const float*)d_in[11];

    _Float16* W0p = (_Float16*)d_ws;
    char* W1q = (char*)d_ws + 262144;
    char* W2q = (char*)d_ws + 1310720;
    char* W3q = (char*)d_ws + 2359296;

    pack_kernel<128><<<16384 / 256, 256, 0, stream>>>(W0, W0p, 16384);
    pack8_kernel<<<65536 / 256, 256, 0, stream>>>(W1, W1q, 65536);
    pack8_kernel<<<65536 / 256, 256, 0, stream>>>(W2, W2q, 65536);
    pack3q_kernel<<<8192 / 256, 256, 0, stream>>>(W3, W3q, 8192);

    node_kernel<<<NBLK, NTHREADS, 0, stream>>>(y0, tarr, W_aug, b_aug,
                                               b0, b1, b2, b3,
                                               W0p, W1q, W2q, W3q,
                                               (float*)d_out);
}

// Round 16
// 3831.784 us; speedup vs baseline: 1.0010x; 1.0010x over previous
//
#include <hip/hip_runtime.h>

typedef _Float16 h8 __attribute__((ext_vector_type(8)));
typedef float f32x4 __attribute__((ext_vector_type(4)));
typedef int  i4 __attribute__((ext_vector_type(4)));

#define NTHREADS 1024
#define ROWS 16
#define NBLK 256   // 4096 tokens / 16 rows

// LDS layout (bytes), total = 160 KiB:
//   buf8A : 16x1024 int8 swizzled @      0 (16384)
//   buf8B : 16x1024 int8 swizzled @  16384 (16384)
//           Yh fp16 16x128 swz    @  16384 ( 4096)  (alias; dead while buf8B live)
//           red i4[512]           @  24576 ( 8192)  (alias; L3 reduce)
//   ring  : 16 waves x 2 slots x 4096 @ 32768 (131072)  async W staging
#define SMEM_BYTES 163840

#define GLOAD16(gp, lp) __builtin_amdgcn_global_load_lds( \
    (const __attribute__((address_space(1))) void*)(gp),  \
    (__attribute__((address_space(3))) void*)(lp), 16, 0, 0)

__device__ __forceinline__ float fast_tanh(float x) {
    float e = __expf(2.0f * x);
    return 1.0f - 2.0f / (e + 1.0f);
}

// flush LDS + block barrier WITHOUT draining vmcnt (keeps async prefetch alive)
__device__ __forceinline__ void lightbar() {
    asm volatile("s_waitcnt lgkmcnt(0)" ::: "memory");
    __builtin_amdgcn_sched_barrier(0);
    __builtin_amdgcn_s_barrier();
    __builtin_amdgcn_sched_barrier(0);
}

// ---------------- weight pack kernels ----------------
template<int K>
__global__ void __launch_bounds__(256) pack_kernel(const float* __restrict__ src,
                                                   _Float16* __restrict__ dst, int nfrag) {
    constexpr int NK = K / 32;
    int idx = blockIdx.x * 256 + threadIdx.x;
    if (idx >= nfrag) return;
    int lane = idx & 63;
    int ct   = (idx >> 6) & 3;
    int kk   = (idx >> 8) % NK;
    int w    = idx / (256 * NK);
    int col  = w * 64 + ct * 16 + (lane & 15);
    int kb   = kk * 32 + (lane >> 4) * 8;
    const float* s = src + (size_t)col * K + kb;
    f32x4 v0 = *(const f32x4*)s;
    f32x4 v1 = *(const f32x4*)(s + 4);
    h8 h;
    h[0]=(_Float16)v0[0]; h[1]=(_Float16)v0[1]; h[2]=(_Float16)v0[2]; h[3]=(_Float16)v0[3];
    h[4]=(_Float16)v1[0]; h[5]=(_Float16)v1[1]; h[6]=(_Float16)v1[2]; h[7]=(_Float16)v1[3];
    *(h8*)(dst + (size_t)idx * 8) = h;
}

__global__ void __launch_bounds__(256) pack8_kernel(const float* __restrict__ src,
                                                    char* __restrict__ dst, int nfrag) {
    int idx = blockIdx.x * 256 + threadIdx.x;
    if (idx >= nfrag) return;
    int lane = idx & 63;
    int ct   = (idx >> 6) & 3;
    int kk   = (idx >> 8) & 15;
    int w    = idx >> 12;
    int col  = w * 64 + ct * 16 + (lane & 15);
    int kb   = kk * 64 + (lane >> 4) * 16;
    const float* s = src + (size_t)col * 1024 + kb;
    union { char q[16]; i4 v; } u;
#pragma unroll
    for (int j = 0; j < 16; ++j)
        u.q[j] = (char)__float2int_rn(s[j] * 4064.0f);   // 32*127
    *(i4*)(dst + (size_t)idx * 16) = u.v;
}

__global__ void __launch_bounds__(256) pack3q_kernel(const float* __restrict__ src,
                                                     char* __restrict__ dst, int nfrag) {
    int idx = blockIdx.x * 256 + threadIdx.x;
    if (idx >= nfrag) return;
    int lane = idx & 63;
    int kk   = (idx >> 6) & 15;
    int cg   = idx >> 10;
    int col  = cg * 16 + (lane & 15);
    int kb   = kk * 64 + (lane >> 4) * 16;
    const float* s = src + (size_t)col * 1024 + kb;
    union { char q[16]; i4 v; } u;
#pragma unroll
    for (int j = 0; j < 16; ++j)
        u.q[j] = (char)__float2int_rn(s[j] * 4064.0f);
    *(i4*)(dst + (size_t)idx * 16) = u.v;
}

// ---------------- layer 0: fp16 x fp16 (K=128), reg ping-pong ----------------
__device__ __forceinline__ void mlp0(const char* __restrict__ src, char* __restrict__ dst,
                                     const _Float16* __restrict__ Wp, f32x4 bv,
                                     int w, int l15, int lhi, int lane)
{
    constexpr int NK = 4;
    const int colbase = w * 64;
    const _Float16* wb = Wp + (size_t)w * NK * 2048 + lane * 8;

    f32x4 acc[4];
#pragma unroll
    for (int ct = 0; ct < 4; ++ct) {
        f32x4 a; a[0] = bv[ct]; a[1] = bv[ct]; a[2] = bv[ct]; a[3] = bv[ct];
        acc[ct] = a;
    }

    h8 bE[4], bO[4], aE, aO;
    auto loadB = [&](h8* b, int kk) {
#pragma unroll
        for (int ct = 0; ct < 4; ++ct)
            b[ct] = *(const h8*)(wb + (size_t)kk * 2048 + ct * 512);
    };
    auto loadA = [&](h8& a, int kk) {
        int byte = (l15 * 256 + kk * 64 + lhi * 16) ^ ((l15 & 7) << 4);
        a = *(const h8*)(src + byte);
    };
    auto mfma4 = [&](h8& a, h8* b) {
        __builtin_amdgcn_s_setprio(1);
#pragma unroll
        for (int ct = 0; ct < 4; ++ct)
            acc[ct] = __builtin_amdgcn_mfma_f32_16x16x32_f16(a, b[ct], acc[ct], 0, 0, 0);
        __builtin_amdgcn_s_setprio(0);
    };

    loadB(bE, 0); loadA(aE, 0);
    loadB(bO, 1); loadA(aO, 1);
    mfma4(aE, bE);
    loadB(bE, 2); loadA(aE, 2);
    mfma4(aO, bO);
    loadB(bO, 3); loadA(aO, 3);
    mfma4(aE, bE);
    mfma4(aO, bO);

#pragma unroll
    for (int ct = 0; ct < 4; ++ct)
#pragma unroll
        for (int j = 0; j < 4; ++j) {
            int row = lhi * 4 + j;
            int gc = colbase + ct * 16 + l15;
            int q = __float2int_rn(fast_tanh(acc[ct][j]) * 127.0f);
            int byte = (row * 1024 + gc) ^ ((row & 7) << 4);
            *(char*)(dst + byte) = (char)q;
        }
}

// ---- async staging: issue chunks 0,1 (4 x 16B gload_lds each) into wave ring ----
__device__ __forceinline__ void stage2(const char* wbl, char* ringW)
{
#pragma unroll
    for (int c = 0; c < 2; ++c) {
        const char* g = wbl + (size_t)c * 4096;
        char* l = ringW + c * 4096;
#pragma unroll
        for (int ct = 0; ct < 4; ++ct)
            GLOAD16(g + ct * 1024, l + ct * 1024);
    }
}

// ------- layers 1/2: int8, B via vmcnt-counted LDS ring; A preloaded in registers -------
__device__ __forceinline__ void mlp8c(const char* __restrict__ src, char* __restrict__ dst,
                                      const char* wbl, char* ringW, const char* ringR,
                                      f32x4 bv, int w, int l15, int lhi,
                                      const char* nextwb)
{
    const int colbase = w * 64;
    i4 acc[4];
#pragma unroll
    for (int ct = 0; ct < 4; ++ct) { i4 z; z[0]=0; z[1]=0; z[2]=0; z[3]=0; acc[ct] = z; }

    // ---- preload all 16 A-fragments (256 B/lane) into registers; static indices ----
    i4 Areg[16];
#pragma unroll
    for (int kk = 0; kk < 16; ++kk) {
        int byte = (l15 * 1024 + kk * 64 + lhi * 16) ^ ((l15 & 7) << 4);
        Areg[kk] = *(const i4*)(src + byte);
    }
    asm volatile("s_waitcnt lgkmcnt(0)" ::: "memory");
    __builtin_amdgcn_sched_barrier(0);

    i4 B0, B1, B2, B3;
    auto readB = [&](int kk) {
        const char* sl = ringR + (kk & 1) * 4096;
        B0 = *(const i4*)(sl);
        B1 = *(const i4*)(sl + 1024);
        B2 = *(const i4*)(sl + 2048);
        B3 = *(const i4*)(sl + 3072);
    };
    auto mfma4 = [&](const i4& A) {
        __builtin_amdgcn_s_setprio(1);
        acc[0] = __builtin_amdgcn_mfma_i32_16x16x64_i8(A, B0, acc[0], 0, 0, 0);
        acc[1] = __builtin_amdgcn_mfma_i32_16x16x64_i8(A, B1, acc[1], 0, 0, 0);
        acc[2] = __builtin_amdgcn_mfma_i32_16x16x64_i8(A, B2, acc[2], 0, 0, 0);
        acc[3] = __builtin_amdgcn_mfma_i32_16x16x64_i8(A, B3, acc[3], 0, 0, 0);
        __builtin_amdgcn_s_setprio(0);
    };

    // fully unrolled chunk loop: static kk everywhere; ring state lives in vmcnt
#pragma unroll
    for (int kk = 0; kk < 15; ++kk) {
        asm volatile("s_waitcnt vmcnt(4)" ::: "memory");   // chunk kk landed
        __builtin_amdgcn_sched_barrier(0);
        readB(kk);
        asm volatile("s_waitcnt lgkmcnt(0)" ::: "memory"); // slot reads done before reuse
        __builtin_amdgcn_sched_barrier(0);
        if (kk < 14) {                                     // issue chunk kk+2 into slot kk&1
            const char* g = wbl + (size_t)(kk + 2) * 4096;
            char* l = ringW + (kk & 1) * 4096;
#pragma unroll
            for (int ct = 0; ct < 4; ++ct)
                GLOAD16(g + ct * 1024, l + ct * 1024);
        }
        __builtin_amdgcn_sched_barrier(0);
        mfma4(Areg[kk]);
    }
    asm volatile("s_waitcnt vmcnt(0)" ::: "memory");       // chunk 15 landed
    __builtin_amdgcn_sched_barrier(0);
    readB(15);
    asm volatile("s_waitcnt lgkmcnt(0)" ::: "memory");
    __builtin_amdgcn_sched_barrier(0);
    // ring fully drained: tail-issue next stage's chunks 0,1
    stage2(nextwb, ringW);
    __builtin_amdgcn_sched_barrier(0);
    mfma4(Areg[15]);

    const float DEQ = 1.0f / 516128.0f;   // 1/(32*127*127)
#pragma unroll
    for (int ct = 0; ct < 4; ++ct) {
        int gc = colbase + ct * 16 + l15;
#pragma unroll
        for (int j = 0; j < 4; ++j) {
            int row = lhi * 4 + j;
            float v = fast_tanh((float)acc[ct][j] * DEQ + bv[ct]);
            int q = __float2int_rn(v * 127.0f);
            int byte = (row * 1024 + gc) ^ ((row & 7) << 4);
            *(char*)(dst + byte) = (char)q;
        }
    }
}

__global__ void
__attribute__((amdgpu_flat_work_group_size(NTHREADS, NTHREADS), amdgpu_waves_per_eu(4, 4)))
node_kernel(const float* __restrict__ y0,
            const float* __restrict__ tarr,
            const float* __restrict__ W_aug,
            const float* __restrict__ b_aug,
            const float* __restrict__ b0,
            const float* __restrict__ b1,
            const float* __restrict__ b2,
            const float* __restrict__ b3,
            const _Float16* __restrict__ W0p,
            const char* __restrict__ W1q,
            const char* __restrict__ W2q,
            const char* __restrict__ W3q,
            float* __restrict__ out)
{
    __shared__ __align__(16) char smem[SMEM_BYTES];
    char* buf8A = smem;
    char* buf8B = smem + 16384;
    char* Yh    = smem + 16384;            // alias buf8B[0:4096]
    i4*   red   = (i4*)(smem + 24576);     // alias buf8B[8192:16384]
    float* Yf   = (float*)smem;            // alias buf8A (init only)
    char* ring  = smem + 32768;

    const int tid  = threadIdx.x;
    const int lane = tid & 63;
    const int w    = tid >> 6;       // 0..15
    const int l15  = lane & 15;
    const int lhi  = lane >> 4;
    const int row0 = blockIdx.x * ROWS;

    const float dtv = tarr[1] - tarr[0];

    // ---- load y0 rows into Yf[:, 0:64] ----
    if (tid < 256) {
        int idx = tid * 4;
        int r = idx >> 6;
        int c = idx & 63;
        f32x4 v = *(const f32x4*)(y0 + (size_t)(row0 + r) * 64 + c);
        *(f32x4*)(Yf + r * 128 + c) = v;
    }
    __syncthreads();

    // ---- augment ----
    {
        int r = tid >> 6;
        int a0 = tid & 63;
        float acc = b_aug[a0];
        for (int d = 0; d < 64; ++d)
            acc += Yf[r * 128 + d] * W_aug[a0 * 64 + d];
        __syncthreads();
        Yf[r * 128 + 64 + a0] = acc;
    }
    __syncthreads();

    // thread-owned state (waves 0..7): col g = w*16+l15, rows lhi*4+j
    const int g = w * 16 + l15;
    f32x4 yreg;
    if (w < 8) {
#pragma unroll
        for (int j = 0; j < 4; ++j)
            yreg[j] = Yf[(lhi * 4 + j) * 128 + g];
    }
    h8 yh0;
    int yh0_byte;
    if (tid < 256) {
        int r = tid >> 4;
        int c = (tid & 15) * 8;
        const float* p = Yf + r * 128 + c;
#pragma unroll
        for (int j = 0; j < 8; ++j) yh0[j] = (_Float16)p[j];
        yh0_byte = ((r * 128 + c) * 2) ^ ((r & 7) << 4);
    }
    __syncthreads();
    if (tid < 256) *(h8*)(Yh + yh0_byte) = yh0;
    __syncthreads();

    // per-wave pointers
    const char* wb1 = W1q + (size_t)w * 65536 + lane * 16;
    const char* wb2 = W2q + (size_t)w * 65536 + lane * 16;
    char* ringW = ring + w * 8192;           // wave-uniform slot base
    const char* ringR = ringW + lane * 16;   // per-lane read base

    // biases in registers (keep vmcnt clean inside mlp8c)
    f32x4 b0v, b1v, b2v;
#pragma unroll
    for (int ct = 0; ct < 4; ++ct) {
        b0v[ct] = b0[w * 64 + ct * 16 + l15];
        b1v[ct] = b1[w * 64 + ct * 16 + l15];
        b2v[ct] = b2[w * 64 + ct * 16 + l15];
    }
    const int cg  = w & 7;
    const int kk0 = (w >> 3) * 8;
    const char* wb3 = W3q + (size_t)cg * 16384 + lane * 16;
    const float b3v = (w < 8) ? b3[g] : 0.0f;
    const float DEQ3 = 1.0f / 516128.0f;

    // prologue: stage L1 chunks 0,1 for step 0
    stage2(wb1, ringW);

    // ---- 31 Euler steps ----
    for (int s = 0; s < 31; ++s) {
        // L0: Yh -> buf8A (L1 chunks already in flight/landed)
        mlp0(Yh, buf8A, W0p, b0v, w, l15, lhi, lane);
        lightbar();

        // L1: buf8A -> buf8B; tail-issues L2 chunks 0,1
        mlp8c(buf8A, buf8B, wb1, ringW, ringR, b1v, w, l15, lhi, wb2);
        lightbar();

        // L2: buf8B -> buf8A; tail-issues NEXT STEP's L1 chunks 0,1
        mlp8c(buf8B, buf8A, wb2, ringW, ringR, b2v, w, l15, lhi, wb1);
        lightbar();

        // L3: DY[16][128] = buf8A @ W3q^T + b3 (int8, K split across wave halves)
        {
            i4 acc3; acc3[0]=0; acc3[1]=0; acc3[2]=0; acc3[3]=0;
            i4 c3E, c3O, x3E, x3O;
            auto loadB3 = [&](i4& b, int kk) {
                b = *(const i4*)(wb3 + (size_t)kk * 1024);
            };
            auto loadA3 = [&](i4& a, int kk) {
                int byte = (l15 * 1024 + kk * 64 + lhi * 16) ^ ((l15 & 7) << 4);
                a = *(const i4*)(buf8A + byte);
            };
            loadB3(c3E, kk0 + 0); loadA3(x3E, kk0 + 0);
#pragma unroll
            for (int q = 0; q < 3; ++q) {
                loadB3(c3O, kk0 + 2 * q + 1); loadA3(x3O, kk0 + 2 * q + 1);
                acc3 = __builtin_amdgcn_mfma_i32_16x16x64_i8(x3E, c3E, acc3, 0, 0, 0);
                loadB3(c3E, kk0 + 2 * q + 2); loadA3(x3E, kk0 + 2 * q + 2);
                acc3 = __builtin_amdgcn_mfma_i32_16x16x64_i8(x3O, c3O, acc3, 0, 0, 0);
            }
            loadB3(c3O, kk0 + 7); loadA3(x3O, kk0 + 7);
            acc3 = __builtin_amdgcn_mfma_i32_16x16x64_i8(x3E, c3E, acc3, 0, 0, 0);
            acc3 = __builtin_amdgcn_mfma_i32_16x16x64_i8(x3O, c3O, acc3, 0, 0, 0);

            if (w >= 8)
                red[cg * 64 + lane] = acc3;
            lightbar();
            if (w < 8) {
                i4 part = red[w * 64 + lane];
#pragma unroll
                for (int j = 0; j < 4; ++j) {
                    int row = lhi * 4 + j;
                    float dy = (float)(acc3[j] + part[j]) * DEQ3 + b3v;
                    float nv = yreg[j] + dtv * dy;
                    yreg[j] = nv;
                    int byte = ((row * 128 + g) * 2) ^ ((row & 7) << 4);
                    *(_Float16*)(Yh + byte) = (_Float16)nv;
                }
            }
        }
        lightbar();
    }

    // drain dangling prefetch (last step tail-issued L1 chunks we never consume)
    asm volatile("s_waitcnt vmcnt(0)" ::: "memory");

    // ---- output ----
    if (w < 4) {
#pragma unroll
        for (int j = 0; j < 4; ++j) {
            int row = lhi * 4 + j;
            out[(size_t)(row0 + row) * 64 + g] = yreg[j];
        }
    }
}

extern "C" void kernel_launch(void* const* d_in, const int* in_sizes, int n_in,
                              void* d_out, int out_size, void* d_ws, size_t ws_size,
                              hipStream_t stream)
{
    const float* y0    = (const float*)d_in[0];
    const float* tarr  = (const float*)d_in[1];
    const float* W_aug = (const float*)d_in[2];
    const float* b_aug = (const float*)d_in[3];
    const float* W0    = (const float*)d_in[4];
    const float* b0    = (const float*)d_in[5];
    const float* W1    = (const float*)d_in[6];
    const float* b1    = (const float*)d_in[7];
    const float* W2    = (const float*)d_in[8];
    const float* b2    = (const float*)d_in[9];
    const float* W3    = (const float*)d_in[10];
    const float* b3    = (const float*)d_in[11];

    _Float16* W0p = (_Float16*)d_ws;
    char* W1q = (char*)d_ws + 262144;
    char* W2q = (char*)d_ws + 1310720;
    char* W3q = (char*)d_ws + 2359296;

    pack_kernel<128><<<16384 / 256, 256, 0, stream>>>(W0, W0p, 16384);
    pack8_kernel<<<65536 / 256, 256, 0, stream>>>(W1, W1q, 65536);
    pack8_kernel<<<65536 / 256, 256, 0, stream>>>(W2, W2q, 65536);
    pack3q_kernel<<<8192 / 256, 256, 0, stream>>>(W3, W3q, 8192);

    node_kernel<<<NBLK, NTHREADS, 0, stream>>>(y0, tarr, W_aug, b_aug,
                                               b0, b1, b2, b3,
                                               W0p, W1q, W2q, W3q,
                                               (float*)d_out);
}

// Round 17
// 3106.727 us; speedup vs baseline: 1.2346x; 1.2334x over previous
//
#include <hip/hip_runtime.h>

typedef _Float16 h8 __attribute__((ext_vector_type(8)));
typedef float f32x4 __attribute__((ext_vector_type(4)));
typedef int  i4 __attribute__((ext_vector_type(4)));

#define NTHREADS 1024
#define ROWS 16
#define NBLK 256   // 4096 tokens / 16 rows

// LDS layout (bytes), total = 160 KiB:
//   buf8A : 16x1024 int8 swizzled @      0 (16384)
//   buf8B : 16x1024 int8 swizzled @  16384 (16384)
//           Yh fp16 16x128 swz    @  16384 ( 4096)  (alias; dead while buf8B live)
//           red i4[512]           @  24576 ( 8192)  (alias; L3 reduce)
//   ring  : 16 waves x 4 slots x 2048 @ 32768 (131072)  async W staging
#define SMEM_BYTES 163840

#define GLOAD16(gp, lp) __builtin_amdgcn_global_load_lds( \
    (const __attribute__((address_space(1))) void*)(gp),  \
    (__attribute__((address_space(3))) void*)(lp), 16, 0, 0)

__device__ __forceinline__ float fast_tanh(float x) {
    float e = __expf(2.0f * x);
    return 1.0f - 2.0f / (e + 1.0f);
}

// flush LDS + block barrier WITHOUT draining vmcnt (keeps async prefetch alive)
__device__ __forceinline__ void lightbar() {
    asm volatile("s_waitcnt lgkmcnt(0)" ::: "memory");
    __builtin_amdgcn_sched_barrier(0);
    __builtin_amdgcn_s_barrier();
    __builtin_amdgcn_sched_barrier(0);
}

// ---------------- weight pack kernels ----------------
template<int K>
__global__ void __launch_bounds__(256) pack_kernel(const float* __restrict__ src,
                                                   _Float16* __restrict__ dst, int nfrag) {
    constexpr int NK = K / 32;
    int idx = blockIdx.x * 256 + threadIdx.x;
    if (idx >= nfrag) return;
    int lane = idx & 63;
    int ct   = (idx >> 6) & 3;
    int kk   = (idx >> 8) % NK;
    int w    = idx / (256 * NK);
    int col  = w * 64 + ct * 16 + (lane & 15);
    int kb   = kk * 32 + (lane >> 4) * 8;
    const float* s = src + (size_t)col * K + kb;
    f32x4 v0 = *(const f32x4*)s;
    f32x4 v1 = *(const f32x4*)(s + 4);
    h8 h;
    h[0]=(_Float16)v0[0]; h[1]=(_Float16)v0[1]; h[2]=(_Float16)v0[2]; h[3]=(_Float16)v0[3];
    h[4]=(_Float16)v1[0]; h[5]=(_Float16)v1[1]; h[6]=(_Float16)v1[2]; h[7]=(_Float16)v1[3];
    *(h8*)(dst + (size_t)idx * 8) = h;
}

__global__ void __launch_bounds__(256) pack8_kernel(const float* __restrict__ src,
                                                    char* __restrict__ dst, int nfrag) {
    int idx = blockIdx.x * 256 + threadIdx.x;
    if (idx >= nfrag) return;
    int lane = idx & 63;
    int ct   = (idx >> 6) & 3;
    int kk   = (idx >> 8) & 15;
    int w    = idx >> 12;
    int col  = w * 64 + ct * 16 + (lane & 15);
    int kb   = kk * 64 + (lane >> 4) * 16;
    const float* s = src + (size_t)col * 1024 + kb;
    union { char q[16]; i4 v; } u;
#pragma unroll
    for (int j = 0; j < 16; ++j)
        u.q[j] = (char)__float2int_rn(s[j] * 4064.0f);   // 32*127
    *(i4*)(dst + (size_t)idx * 16) = u.v;
}

__global__ void __launch_bounds__(256) pack3q_kernel(const float* __restrict__ src,
                                                     char* __restrict__ dst, int nfrag) {
    int idx = blockIdx.x * 256 + threadIdx.x;
    if (idx >= nfrag) return;
    int lane = idx & 63;
    int kk   = (idx >> 6) & 15;
    int cg   = idx >> 10;
    int col  = cg * 16 + (lane & 15);
    int kb   = kk * 64 + (lane >> 4) * 16;
    const float* s = src + (size_t)col * 1024 + kb;
    union { char q[16]; i4 v; } u;
#pragma unroll
    for (int j = 0; j < 16; ++j)
        u.q[j] = (char)__float2int_rn(s[j] * 4064.0f);
    *(i4*)(dst + (size_t)idx * 16) = u.v;
}

// ---------------- layer 0: fp16 x fp16 (K=128), reg ping-pong ----------------
__device__ __forceinline__ void mlp0(const char* __restrict__ src, char* __restrict__ dst,
                                     const _Float16* __restrict__ Wp, f32x4 bv,
                                     int w, int l15, int lhi, int lane)
{
    constexpr int NK = 4;
    const int colbase = w * 64;
    const _Float16* wb = Wp + (size_t)w * NK * 2048 + lane * 8;

    f32x4 acc[4];
#pragma unroll
    for (int ct = 0; ct < 4; ++ct) {
        f32x4 a; a[0] = bv[ct]; a[1] = bv[ct]; a[2] = bv[ct]; a[3] = bv[ct];
        acc[ct] = a;
    }

    h8 bE[4], bO[4], aE, aO;
    auto loadB = [&](h8* b, int kk) {
#pragma unroll
        for (int ct = 0; ct < 4; ++ct)
            b[ct] = *(const h8*)(wb + (size_t)kk * 2048 + ct * 512);
    };
    auto loadA = [&](h8& a, int kk) {
        int byte = (l15 * 256 + kk * 64 + lhi * 16) ^ ((l15 & 7) << 4);
        a = *(const h8*)(src + byte);
    };
    auto mfma4 = [&](h8& a, h8* b) {
        __builtin_amdgcn_s_setprio(1);
#pragma unroll
        for (int ct = 0; ct < 4; ++ct)
            acc[ct] = __builtin_amdgcn_mfma_f32_16x16x32_f16(a, b[ct], acc[ct], 0, 0, 0);
        __builtin_amdgcn_s_setprio(0);
    };

    loadB(bE, 0); loadA(aE, 0);
    loadB(bO, 1); loadA(aO, 1);
    mfma4(aE, bE);
    loadB(bE, 2); loadA(aE, 2);
    mfma4(aO, bO);
    loadB(bO, 3); loadA(aO, 3);
    mfma4(aE, bE);
    mfma4(aO, bO);

#pragma unroll
    for (int ct = 0; ct < 4; ++ct)
#pragma unroll
        for (int j = 0; j < 4; ++j) {
            int row = lhi * 4 + j;
            int gc = colbase + ct * 16 + l15;
            int q = __float2int_rn(fast_tanh(acc[ct][j]) * 127.0f);
            int byte = (row * 1024 + gc) ^ ((row & 7) << 4);
            *(char*)(dst + byte) = (char)q;
        }
}

// ---- async staging: one 2KB chunk = 2 x 16B-per-lane gloads ----
__device__ __forceinline__ void stage_chunk(const char* g, char* l) {
    GLOAD16(g, l);
    GLOAD16(g + 1024, l + 1024);
}

// prologue: chunks 0,1,2 into slots 0,1,2 (6 loads outstanding)
__device__ __forceinline__ void stage3(const char* wbl, char* ringW) {
#pragma unroll
    for (int c = 0; c < 3; ++c)
        stage_chunk(wbl + (size_t)c * 2048, ringW + (c & 3) * 2048);
}

// ------- layers 1/2: int8, 4-slot 2KB-chunk ring, depth-3 prefetch, issue-before-read -------
// Chunk c (0..31): kk = c>>1, ct-pair = c&1. Tail chunks (c+3 >= 32) stage next layer's 0..2.
__device__ __forceinline__ void mlp8c(const char* __restrict__ src, char* __restrict__ dst,
                                      const char* wbl, const char* nextwb,
                                      char* ringW, const char* ringR,
                                      f32x4 bv, int w, int l15, int lhi)
{
    const int colbase = w * 64;
    i4 acc[4];
#pragma unroll
    for (int ct = 0; ct < 4; ++ct) { i4 z; z[0]=0; z[1]=0; z[2]=0; z[3]=0; acc[ct] = z; }

    i4 A{}, B0, B1;

#pragma unroll
    for (int c = 0; c < 32; ++c) {
        asm volatile("s_waitcnt vmcnt(4)" ::: "memory");   // chunk c (2 oldest loads) landed
        __builtin_amdgcn_sched_barrier(0);
        // issue chunk c+3 into slot (c+3)&3 == (c-1)&3: reads of that slot finished at iter c-1
        {
            const char* g = (c + 3 < 32) ? (wbl + (size_t)(c + 3) * 2048)
                                         : (nextwb + (size_t)(c + 3 - 32) * 2048);
            char* l = ringW + ((c + 3) & 3) * 2048;
            stage_chunk(g, l);
        }
        __builtin_amdgcn_sched_barrier(0);
        // read B fragments of chunk c; A once per K-step (even c)
        {
            const char* sl = ringR + (c & 3) * 2048;
            B0 = *(const i4*)(sl);
            B1 = *(const i4*)(sl + 1024);
        }
        if ((c & 1) == 0) {
            int kk = c >> 1;
            int byte = (l15 * 1024 + kk * 64 + lhi * 16) ^ ((l15 & 7) << 4);
            A = *(const i4*)(src + byte);
        }
        asm volatile("s_waitcnt lgkmcnt(0)" ::: "memory");
        __builtin_amdgcn_sched_barrier(0);
        __builtin_amdgcn_s_setprio(1);
        if ((c & 1) == 0) {
            acc[0] = __builtin_amdgcn_mfma_i32_16x16x64_i8(A, B0, acc[0], 0, 0, 0);
            acc[1] = __builtin_amdgcn_mfma_i32_16x16x64_i8(A, B1, acc[1], 0, 0, 0);
        } else {
            acc[2] = __builtin_amdgcn_mfma_i32_16x16x64_i8(A, B0, acc[2], 0, 0, 0);
            acc[3] = __builtin_amdgcn_mfma_i32_16x16x64_i8(A, B1, acc[3], 0, 0, 0);
        }
        __builtin_amdgcn_s_setprio(0);
    }

    const float DEQ = 1.0f / 516128.0f;   // 1/(32*127*127)
#pragma unroll
    for (int ct = 0; ct < 4; ++ct) {
        int gc = colbase + ct * 16 + l15;
#pragma unroll
        for (int j = 0; j < 4; ++j) {
            int row = lhi * 4 + j;
            float v = fast_tanh((float)acc[ct][j] * DEQ + bv[ct]);
            int q = __float2int_rn(v * 127.0f);
            int byte = (row * 1024 + gc) ^ ((row & 7) << 4);
            *(char*)(dst + byte) = (char)q;
        }
    }
}

__global__ void
__attribute__((amdgpu_flat_work_group_size(NTHREADS, NTHREADS)))
node_kernel(const float* __restrict__ y0,
            const float* __restrict__ tarr,
            const float* __restrict__ W_aug,
            const float* __restrict__ b_aug,
            const float* __restrict__ b0,
            const float* __restrict__ b1,
            const float* __restrict__ b2,
            const float* __restrict__ b3,
            const _Float16* __restrict__ W0p,
            const char* __restrict__ W1q,
            const char* __restrict__ W2q,
            const char* __restrict__ W3q,
            float* __restrict__ out)
{
    __shared__ __align__(16) char smem[SMEM_BYTES];
    char* buf8A = smem;
    char* buf8B = smem + 16384;
    char* Yh    = smem + 16384;            // alias buf8B[0:4096]
    i4*   red   = (i4*)(smem + 24576);     // alias buf8B[8192:16384]
    float* Yf   = (float*)smem;            // alias buf8A (init only)
    char* ring  = smem + 32768;

    const int tid  = threadIdx.x;
    const int lane = tid & 63;
    const int w    = tid >> 6;       // 0..15
    const int l15  = lane & 15;
    const int lhi  = lane >> 4;
    const int row0 = blockIdx.x * ROWS;

    const float dtv = tarr[1] - tarr[0];

    // ---- load y0 rows into Yf[:, 0:64] ----
    if (tid < 256) {
        int idx = tid * 4;
        int r = idx >> 6;
        int c = idx & 63;
        f32x4 v = *(const f32x4*)(y0 + (size_t)(row0 + r) * 64 + c);
        *(f32x4*)(Yf + r * 128 + c) = v;
    }
    __syncthreads();

    // ---- augment ----
    {
        int r = tid >> 6;
        int a0 = tid & 63;
        float acc = b_aug[a0];
        for (int d = 0; d < 64; ++d)
            acc += Yf[r * 128 + d] * W_aug[a0 * 64 + d];
        __syncthreads();
        Yf[r * 128 + 64 + a0] = acc;
    }
    __syncthreads();

    // thread-owned state (waves 0..7): col g = w*16+l15, rows lhi*4+j
    const int g = w * 16 + l15;
    f32x4 yreg;
    if (w < 8) {
#pragma unroll
        for (int j = 0; j < 4; ++j)
            yreg[j] = Yf[(lhi * 4 + j) * 128 + g];
    }
    h8 yh0;
    int yh0_byte;
    if (tid < 256) {
        int r = tid >> 4;
        int c = (tid & 15) * 8;
        const float* p = Yf + r * 128 + c;
#pragma unroll
        for (int j = 0; j < 8; ++j) yh0[j] = (_Float16)p[j];
        yh0_byte = ((r * 128 + c) * 2) ^ ((r & 7) << 4);
    }
    __syncthreads();
    if (tid < 256) *(h8*)(Yh + yh0_byte) = yh0;
    __syncthreads();

    // per-wave pointers
    const char* wb1 = W1q + (size_t)w * 65536 + lane * 16;
    const char* wb2 = W2q + (size_t)w * 65536 + lane * 16;
    char* ringW = ring + w * 8192;           // wave-uniform slot base (4 x 2KB)
    const char* ringR = ringW + lane * 16;   // per-lane read base

    // biases in registers (keep vmcnt clean inside mlp8c)
    f32x4 b0v, b1v, b2v;
#pragma unroll
    for (int ct = 0; ct < 4; ++ct) {
        b0v[ct] = b0[w * 64 + ct * 16 + l15];
        b1v[ct] = b1[w * 64 + ct * 16 + l15];
        b2v[ct] = b2[w * 64 + ct * 16 + l15];
    }
    const int cg  = w & 7;
    const int kk0 = (w >> 3) * 8;
    const char* wb3 = W3q + (size_t)cg * 16384 + lane * 16;
    const float b3v = (w < 8) ? b3[g] : 0.0f;
    const float DEQ3 = 1.0f / 516128.0f;

    // prologue: stage L1 chunks 0,1,2 for step 0
    stage3(wb1, ringW);

    // ---- 31 Euler steps ----
    for (int s = 0; s < 31; ++s) {
        // L0: Yh -> buf8A (L1 chunks already in flight/landed)
        mlp0(Yh, buf8A, W0p, b0v, w, l15, lhi, lane);
        lightbar();

        // L1: buf8A -> buf8B; tail auto-stages L2 chunks 0,1,2
        mlp8c(buf8A, buf8B, wb1, wb2, ringW, ringR, b1v, w, l15, lhi);
        lightbar();

        // L2: buf8B -> buf8A; tail auto-stages NEXT STEP's L1 chunks 0,1,2
        mlp8c(buf8B, buf8A, wb2, wb1, ringW, ringR, b2v, w, l15, lhi);
        lightbar();

        // L3: DY[16][128] = buf8A @ W3q^T + b3 (int8, K split across wave halves)
        {
            i4 acc3; acc3[0]=0; acc3[1]=0; acc3[2]=0; acc3[3]=0;
            i4 c3E, c3O, x3E, x3O;
            auto loadB3 = [&](i4& b, int kk) {
                b = *(const i4*)(wb3 + (size_t)kk * 1024);
            };
            auto loadA3 = [&](i4& a, int kk) {
                int byte = (l15 * 1024 + kk * 64 + lhi * 16) ^ ((l15 & 7) << 4);
                a = *(const i4*)(buf8A + byte);
            };
            loadB3(c3E, kk0 + 0); loadA3(x3E, kk0 + 0);
#pragma unroll
            for (int q = 0; q < 3; ++q) {
                loadB3(c3O, kk0 + 2 * q + 1); loadA3(x3O, kk0 + 2 * q + 1);
                acc3 = __builtin_amdgcn_mfma_i32_16x16x64_i8(x3E, c3E, acc3, 0, 0, 0);
                loadB3(c3E, kk0 + 2 * q + 2); loadA3(x3E, kk0 + 2 * q + 2);
                acc3 = __builtin_amdgcn_mfma_i32_16x16x64_i8(x3O, c3O, acc3, 0, 0, 0);
            }
            loadB3(c3O, kk0 + 7); loadA3(x3O, kk0 + 7);
            acc3 = __builtin_amdgcn_mfma_i32_16x16x64_i8(x3E, c3E, acc3, 0, 0, 0);
            acc3 = __builtin_amdgcn_mfma_i32_16x16x64_i8(x3O, c3O, acc3, 0, 0, 0);

            if (w >= 8)
                red[cg * 64 + lane] = acc3;
            lightbar();
            if (w < 8) {
                i4 part = red[w * 64 + lane];
#pragma unroll
                for (int j = 0; j < 4; ++j) {
                    int row = lhi * 4 + j;
                    float dy = (float)(acc3[j] + part[j]) * DEQ3 + b3v;
                    float nv = yreg[j] + dtv * dy;
                    yreg[j] = nv;
                    int byte = ((row * 128 + g) * 2) ^ ((row & 7) << 4);
                    *(_Float16*)(Yh + byte) = (_Float16)nv;
                }
            }
        }
        lightbar();
    }

    // drain dangling prefetch (last step tail-staged L1 chunks we never consume)
    asm volatile("s_waitcnt vmcnt(0)" ::: "memory");

    // ---- output ----
    if (w < 4) {
#pragma unroll
        for (int j = 0; j < 4; ++j) {
            int row = lhi * 4 + j;
            out[(size_t)(row0 + row) * 64 + g] = yreg[j];
        }
    }
}

extern "C" void kernel_launch(void* const* d_in, const int* in_sizes, int n_in,
                              void* d_out, int out_size, void* d_ws, size_t ws_size,
                              hipStream_t stream)
{
    const float* y0    = (const float*)d_in[0];
    const float* tarr  = (const float*)d_in[1];
    const float* W_aug = (const float*)d_in[2];
    const float* b_aug = (const float*)d_in[3];
    const float* W0    = (const float*)d_in[4];
    const float* b0    = (const float*)d_in[5];
    const float* W1    = (const float*)d_in[6];
    const float* b1    = (const float*)d_in[7];
    const float* W2    = (const float*)d_in[8];
    const float* b2    = (const float*)d_in[9];
    const float* W3    = (const float*)d_in[10];
    const float* b3    = (const float*)d_in[11];

    _Float16* W0p = (_Float16*)d_ws;
    char* W1q = (char*)d_ws + 262144;
    char* W2q = (char*)d_ws + 1310720;
    char* W3q = (char*)d_ws + 2359296;

    pack_kernel<128><<<16384 / 256, 256, 0, stream>>>(W0, W0p, 16384);
    pack8_kernel<<<65536 / 256, 256, 0, stream>>>(W1, W1q, 65536);
    pack8_kernel<<<65536 / 256, 256, 0, stream>>>(W2, W2q, 65536);
    pack3q_kernel<<<8192 / 256, 256, 0, stream>>>(W3, W3q, 8192);

    node_kernel<<<NBLK, NTHREADS, 0, stream>>>(y0, tarr, W_aug, b_aug,
                                               b0, b1, b2, b3,
                                               W0p, W1q, W2q, W3q,
                                               (float*)d_out);
}

// Round 18
// 1241.199 us; speedup vs baseline: 3.0901x; 2.5030x over previous
//
#include <hip/hip_runtime.h>

typedef _Float16 h8 __attribute__((ext_vector_type(8)));
typedef float f32x4 __attribute__((ext_vector_type(4)));
typedef int  i4 __attribute__((ext_vector_type(4)));

#define NTHREADS 1024
#define ROWS 16
#define NBLK 256   // 4096 tokens / 16 rows

// LDS layout (bytes), total = 160 KiB:
//   buf8A : 16x1024 int8 swizzled @      0 (16384)
//   buf8B : 16x1024 int8 swizzled @  16384 (16384)
//           Yh fp16 16x128 swz    @  16384 ( 4096)  (alias; dead while buf8B live)
//           red i4[512]           @  24576 ( 8192)  (alias; L3 reduce)
//   ring  : 16 waves x 2 slots x 4096 @ 32768 (131072)  async W staging
#define SMEM_BYTES 163840

#define GLOAD16(gp, lp) __builtin_amdgcn_global_load_lds( \
    (const __attribute__((address_space(1))) void*)(gp),  \
    (__attribute__((address_space(3))) void*)(lp), 16, 0, 0)

__device__ __forceinline__ float fast_tanh(float x) {
    float e = __expf(2.0f * x);
    return 1.0f - 2.0f / (e + 1.0f);
}

// flush LDS + block barrier WITHOUT draining vmcnt (keeps async prefetch alive)
__device__ __forceinline__ void lightbar() {
    asm volatile("s_waitcnt lgkmcnt(0)" ::: "memory");
    __builtin_amdgcn_sched_barrier(0);
    __builtin_amdgcn_s_barrier();
    __builtin_amdgcn_sched_barrier(0);
}

// ---------------- weight pack kernels ----------------
template<int K>
__global__ void __launch_bounds__(256) pack_kernel(const float* __restrict__ src,
                                                   _Float16* __restrict__ dst, int nfrag) {
    constexpr int NK = K / 32;
    int idx = blockIdx.x * 256 + threadIdx.x;
    if (idx >= nfrag) return;
    int lane = idx & 63;
    int ct   = (idx >> 6) & 3;
    int kk   = (idx >> 8) % NK;
    int w    = idx / (256 * NK);
    int col  = w * 64 + ct * 16 + (lane & 15);
    int kb   = kk * 32 + (lane >> 4) * 8;
    const float* s = src + (size_t)col * K + kb;
    f32x4 v0 = *(const f32x4*)s;
    f32x4 v1 = *(const f32x4*)(s + 4);
    h8 h;
    h[0]=(_Float16)v0[0]; h[1]=(_Float16)v0[1]; h[2]=(_Float16)v0[2]; h[3]=(_Float16)v0[3];
    h[4]=(_Float16)v1[0]; h[5]=(_Float16)v1[1]; h[6]=(_Float16)v1[2]; h[7]=(_Float16)v1[3];
    *(h8*)(dst + (size_t)idx * 8) = h;
}

__global__ void __launch_bounds__(256) pack8_kernel(const float* __restrict__ src,
                                                    char* __restrict__ dst, int nfrag) {
    int idx = blockIdx.x * 256 + threadIdx.x;
    if (idx >= nfrag) return;
    int lane = idx & 63;
    int ct   = (idx >> 6) & 3;
    int kk   = (idx >> 8) & 15;
    int w    = idx >> 12;
    int col  = w * 64 + ct * 16 + (lane & 15);
    int kb   = kk * 64 + (lane >> 4) * 16;
    const float* s = src + (size_t)col * 1024 + kb;
    union { char q[16]; i4 v; } u;
#pragma unroll
    for (int j = 0; j < 16; ++j)
        u.q[j] = (char)__float2int_rn(s[j] * 4064.0f);   // 32*127
    *(i4*)(dst + (size_t)idx * 16) = u.v;
}

__global__ void __launch_bounds__(256) pack3q_kernel(const float* __restrict__ src,
                                                     char* __restrict__ dst, int nfrag) {
    int idx = blockIdx.x * 256 + threadIdx.x;
    if (idx >= nfrag) return;
    int lane = idx & 63;
    int kk   = (idx >> 6) & 15;
    int cg   = idx >> 10;
    int col  = cg * 16 + (lane & 15);
    int kb   = kk * 64 + (lane >> 4) * 16;
    const float* s = src + (size_t)col * 1024 + kb;
    union { char q[16]; i4 v; } u;
#pragma unroll
    for (int j = 0; j < 16; ++j)
        u.q[j] = (char)__float2int_rn(s[j] * 4064.0f);
    *(i4*)(dst + (size_t)idx * 16) = u.v;
}

// ---------------- layer 0: fp16 x fp16 (K=128), reg ping-pong ----------------
__device__ __forceinline__ void mlp0(const char* __restrict__ src, char* __restrict__ dst,
                                     const _Float16* __restrict__ Wp, f32x4 bv,
                                     int w, int l15, int lhi, int lane)
{
    constexpr int NK = 4;
    const int colbase = w * 64;
    const _Float16* wb = Wp + (size_t)w * NK * 2048 + lane * 8;

    f32x4 acc[4];
#pragma unroll
    for (int ct = 0; ct < 4; ++ct) {
        f32x4 a; a[0] = bv[ct]; a[1] = bv[ct]; a[2] = bv[ct]; a[3] = bv[ct];
        acc[ct] = a;
    }

    h8 bE[4], bO[4], aE, aO;
    auto loadB = [&](h8* b, int kk) {
#pragma unroll
        for (int ct = 0; ct < 4; ++ct)
            b[ct] = *(const h8*)(wb + (size_t)kk * 2048 + ct * 512);
    };
    auto loadA = [&](h8& a, int kk) {
        int byte = (l15 * 256 + kk * 64 + lhi * 16) ^ ((l15 & 7) << 4);
        a = *(const h8*)(src + byte);
    };
    auto mfma4 = [&](h8& a, h8* b) {
        __builtin_amdgcn_s_setprio(1);
#pragma unroll
        for (int ct = 0; ct < 4; ++ct)
            acc[ct] = __builtin_amdgcn_mfma_f32_16x16x32_f16(a, b[ct], acc[ct], 0, 0, 0);
        __builtin_amdgcn_s_setprio(0);
    };

    loadB(bE, 0); loadA(aE, 0);
    loadB(bO, 1); loadA(aO, 1);
    mfma4(aE, bE);
    loadB(bE, 2); loadA(aE, 2);
    mfma4(aO, bO);
    loadB(bO, 3); loadA(aO, 3);
    mfma4(aE, bE);
    mfma4(aO, bO);

#pragma unroll
    for (int ct = 0; ct < 4; ++ct)
#pragma unroll
        for (int j = 0; j < 4; ++j) {
            int row = lhi * 4 + j;
            int gc = colbase + ct * 16 + l15;
            int q = __float2int_rn(fast_tanh(acc[ct][j]) * 127.0f);
            int byte = (row * 1024 + gc) ^ ((row & 7) << 4);
            *(char*)(dst + byte) = (char)q;
        }
}

// ---- async staging: issue chunks 0,1 (4 x 16B gload_lds each) into wave ring ----
__device__ __forceinline__ void stage2(const char* wbl, char* ringW)
{
#pragma unroll
    for (int c = 0; c < 2; ++c) {
        const char* g = wbl + (size_t)c * 4096;
        char* l = ringW + c * 4096;
#pragma unroll
        for (int ct = 0; ct < 4; ++ct)
            GLOAD16(g + ct * 1024, l + ct * 1024);
    }
}

// ------- layers 1/2: int8, B via vmcnt-counted LDS ring; tail-issues next stage -------
__device__ __forceinline__ void mlp8c(const char* __restrict__ src, char* __restrict__ dst,
                                      const char* wbl, char* ringW, const char* ringR,
                                      f32x4 bv, int w, int l15, int lhi,
                                      const char* nextwb)
{
    const int colbase = w * 64;
    i4 acc[4];
#pragma unroll
    for (int ct = 0; ct < 4; ++ct) { i4 z; z[0]=0; z[1]=0; z[2]=0; z[3]=0; acc[ct] = z; }

    i4 B0, B1, B2, B3, A;
    auto readSlot = [&](int kk) {
        const char* sl = ringR + (kk & 1) * 4096;
        B0 = *(const i4*)(sl);
        B1 = *(const i4*)(sl + 1024);
        B2 = *(const i4*)(sl + 2048);
        B3 = *(const i4*)(sl + 3072);
        int byte = (l15 * 1024 + kk * 64 + lhi * 16) ^ ((l15 & 7) << 4);
        A = *(const i4*)(src + byte);
    };
    auto mfma4 = [&]() {
        __builtin_amdgcn_s_setprio(1);
        acc[0] = __builtin_amdgcn_mfma_i32_16x16x64_i8(A, B0, acc[0], 0, 0, 0);
        acc[1] = __builtin_amdgcn_mfma_i32_16x16x64_i8(A, B1, acc[1], 0, 0, 0);
        acc[2] = __builtin_amdgcn_mfma_i32_16x16x64_i8(A, B2, acc[2], 0, 0, 0);
        acc[3] = __builtin_amdgcn_mfma_i32_16x16x64_i8(A, B3, acc[3], 0, 0, 0);
        __builtin_amdgcn_s_setprio(0);
    };

    // entry state: chunks 0,1 already issued earlier (may have landed — waits are conservative)
#pragma unroll 1
    for (int kk = 0; kk < 15; ++kk) {
        asm volatile("s_waitcnt vmcnt(4)" ::: "memory");   // chunk kk landed
        __builtin_amdgcn_sched_barrier(0);
        readSlot(kk);
        asm volatile("s_waitcnt lgkmcnt(0)" ::: "memory"); // slot reads done before reuse
        __builtin_amdgcn_sched_barrier(0);
        if (kk < 14) {                                     // issue chunk kk+2 into slot kk&1
            const char* g = wbl + (size_t)(kk + 2) * 4096;
            char* l = ringW + (kk & 1) * 4096;
#pragma unroll
            for (int ct = 0; ct < 4; ++ct)
                GLOAD16(g + ct * 1024, l + ct * 1024);
        }
        __builtin_amdgcn_sched_barrier(0);
        mfma4();
    }
    asm volatile("s_waitcnt vmcnt(0)" ::: "memory");       // chunk 15 landed
    __builtin_amdgcn_sched_barrier(0);
    readSlot(15);
    asm volatile("s_waitcnt lgkmcnt(0)" ::: "memory");
    __builtin_amdgcn_sched_barrier(0);
    // ring fully drained: tail-issue next stage's chunks 0,1 (hides under epilogue+barrier+next phase)
    stage2(nextwb, ringW);
    __builtin_amdgcn_sched_barrier(0);
    mfma4();

    const float DEQ = 1.0f / 516128.0f;   // 1/(32*127*127)
#pragma unroll
    for (int ct = 0; ct < 4; ++ct) {
        int gc = colbase + ct * 16 + l15;
#pragma unroll
        for (int j = 0; j < 4; ++j) {
            int row = lhi * 4 + j;
            float v = fast_tanh((float)acc[ct][j] * DEQ + bv[ct]);
            int q = __float2int_rn(v * 127.0f);
            int byte = (row * 1024 + gc) ^ ((row & 7) << 4);
            *(char*)(dst + byte) = (char)q;
        }
    }
}

__global__ void
__attribute__((amdgpu_flat_work_group_size(NTHREADS, NTHREADS)))
node_kernel(const float* __restrict__ y0,
            const float* __restrict__ tarr,
            const float* __restrict__ W_aug,
            const float* __restrict__ b_aug,
            const float* __restrict__ b0,
            const float* __restrict__ b1,
            const float* __restrict__ b2,
            const float* __restrict__ b3,
            const _Float16* __restrict__ W0p,
            const char* __restrict__ W1q,
            const char* __restrict__ W2q,
            const char* __restrict__ W3q,
            float* __restrict__ out)
{
    __shared__ __align__(16) char smem[SMEM_BYTES];
    char* buf8A = smem;
    char* buf8B = smem + 16384;
    char* Yh    = smem + 16384;            // alias buf8B[0:4096]
    i4*   red   = (i4*)(smem + 24576);     // alias buf8B[8192:16384]
    float* Yf   = (float*)smem;            // alias buf8A (init only)
    char* ring  = smem + 32768;

    const int tid  = threadIdx.x;
    const int lane = tid & 63;
    const int w    = tid >> 6;       // 0..15
    const int l15  = lane & 15;
    const int lhi  = lane >> 4;
    const int row0 = blockIdx.x * ROWS;

    const float dtv = tarr[1] - tarr[0];

    // ---- load y0 rows into Yf[:, 0:64] ----
    if (tid < 256) {
        int idx = tid * 4;
        int r = idx >> 6;
        int c = idx & 63;
        f32x4 v = *(const f32x4*)(y0 + (size_t)(row0 + r) * 64 + c);
        *(f32x4*)(Yf + r * 128 + c) = v;
    }
    __syncthreads();

    // ---- augment ----
    {
        int r = tid >> 6;
        int a0 = tid & 63;
        float acc = b_aug[a0];
        for (int d = 0; d < 64; ++d)
            acc += Yf[r * 128 + d] * W_aug[a0 * 64 + d];
        __syncthreads();
        Yf[r * 128 + 64 + a0] = acc;
    }
    __syncthreads();

    // thread-owned state (waves 0..7): col g = w*16+l15, rows lhi*4+j
    const int g = w * 16 + l15;
    f32x4 yreg;
    if (w < 8) {
#pragma unroll
        for (int j = 0; j < 4; ++j)
            yreg[j] = Yf[(lhi * 4 + j) * 128 + g];
    }
    h8 yh0;
    int yh0_byte;
    if (tid < 256) {
        int r = tid >> 4;
        int c = (tid & 15) * 8;
        const float* p = Yf + r * 128 + c;
#pragma unroll
        for (int j = 0; j < 8; ++j) yh0[j] = (_Float16)p[j];
        yh0_byte = ((r * 128 + c) * 2) ^ ((r & 7) << 4);
    }
    __syncthreads();
    if (tid < 256) *(h8*)(Yh + yh0_byte) = yh0;
    __syncthreads();

    // per-wave pointers
    const char* wb1 = W1q + (size_t)w * 65536 + lane * 16;
    const char* wb2 = W2q + (size_t)w * 65536 + lane * 16;
    char* ringW = ring + w * 8192;           // wave-uniform slot base
    const char* ringR = ringW + lane * 16;   // per-lane read base

    // biases in registers (keep vmcnt clean inside mlp8c)
    f32x4 b0v, b1v, b2v;
#pragma unroll
    for (int ct = 0; ct < 4; ++ct) {
        b0v[ct] = b0[w * 64 + ct * 16 + l15];
        b1v[ct] = b1[w * 64 + ct * 16 + l15];
        b2v[ct] = b2[w * 64 + ct * 16 + l15];
    }
    const int cg  = w & 7;
    const int kk0 = (w >> 3) * 8;
    const char* wb3 = W3q + (size_t)cg * 16384 + lane * 16;
    const float b3v = (w < 8) ? b3[g] : 0.0f;
    const float DEQ3 = 1.0f / 516128.0f;

    // prologue: stage L1 chunks 0,1 for step 0
    stage2(wb1, ringW);

    // ---- 31 Euler steps ----
    for (int s = 0; s < 31; ++s) {
        // L0: Yh -> buf8A (L1 chunks already in flight/landed)
        mlp0(Yh, buf8A, W0p, b0v, w, l15, lhi, lane);
        lightbar();

        // L1: buf8A -> buf8B; tail-issues L2 chunks 0,1
        mlp8c(buf8A, buf8B, wb1, ringW, ringR, b1v, w, l15, lhi, wb2);
        lightbar();

        // L2: buf8B -> buf8A; tail-issues NEXT STEP's L1 chunks 0,1
        mlp8c(buf8B, buf8A, wb2, ringW, ringR, b2v, w, l15, lhi, wb1);
        lightbar();

        // L3: DY[16][128] = buf8A @ W3q^T + b3 (int8, K split across wave halves)
        {
            i4 acc3; acc3[0]=0; acc3[1]=0; acc3[2]=0; acc3[3]=0;
            i4 c3E, c3O, x3E, x3O;
            auto loadB3 = [&](i4& b, int kk) {
                b = *(const i4*)(wb3 + (size_t)kk * 1024);
            };
            auto loadA3 = [&](i4& a, int kk) {
                int byte = (l15 * 1024 + kk * 64 + lhi * 16) ^ ((l15 & 7) << 4);
                a = *(const i4*)(buf8A + byte);
            };
            loadB3(c3E, kk0 + 0); loadA3(x3E, kk0 + 0);
#pragma unroll
            for (int q = 0; q < 3; ++q) {
                loadB3(c3O, kk0 + 2 * q + 1); loadA3(x3O, kk0 + 2 * q + 1);
                acc3 = __builtin_amdgcn_mfma_i32_16x16x64_i8(x3E, c3E, acc3, 0, 0, 0);
                loadB3(c3E, kk0 + 2 * q + 2); loadA3(x3E, kk0 + 2 * q + 2);
                acc3 = __builtin_amdgcn_mfma_i32_16x16x64_i8(x3O, c3O, acc3, 0, 0, 0);
            }
            loadB3(c3O, kk0 + 7); loadA3(x3O, kk0 + 7);
            acc3 = __builtin_amdgcn_mfma_i32_16x16x64_i8(x3E, c3E, acc3, 0, 0, 0);
            acc3 = __builtin_amdgcn_mfma_i32_16x16x64_i8(x3O, c3O, acc3, 0, 0, 0);

            if (w >= 8)
                red[cg * 64 + lane] = acc3;
            lightbar();
            if (w < 8) {
                i4 part = red[w * 64 + lane];
#pragma unroll
                for (int j = 0; j < 4; ++j) {
                    int row = lhi * 4 + j;
                    float dy = (float)(acc3[j] + part[j]) * DEQ3 + b3v;
                    float nv = yreg[j] + dtv * dy;
                    yreg[j] = nv;
                    int byte = ((row * 128 + g) * 2) ^ ((row & 7) << 4);
                    *(_Float16*)(Yh + byte) = (_Float16)nv;
                }
            }
        }
        lightbar();
    }

    // drain dangling prefetch (last step tail-issued L1 chunks we never consume)
    asm volatile("s_waitcnt vmcnt(0)" ::: "memory");

    // ---- output ----
    if (w < 4) {
#pragma unroll
        for (int j = 0; j < 4; ++j) {
            int row = lhi * 4 + j;
            out[(size_t)(row0 + row) * 64 + g] = yreg[j];
        }
    }
}

extern "C" void kernel_launch(void* const* d_in, const int* in_sizes, int n_in,
                              void* d_out, int out_size, void* d_ws, size_t ws_size,
                              hipStream_t stream)
{
    const float* y0    = (const float*)d_in[0];
    const float* tarr  = (const float*)d_in[1];
    const float* W_aug = (const float*)d_in[2];
    const float* b_aug = (const float*)d_in[3];
    const float* W0    = (const float*)d_in[4];
    const float* b0    = (const float*)d_in[5];
    const float* W1    = (const float*)d_in[6];
    const float* b1    = (const float*)d_in[7];
    const float* W2    = (const float*)d_in[8];
    const float* b2    = (const float*)d_in[9];
    const float* W3    = (const float*)d_in[10];
    const float* b3    = (const float*)d_in[11];

    _Float16* W0p = (_Float16*)d_ws;
    char* W1q = (char*)d_ws + 262144;
    char* W2q = (char*)d_ws + 1310720;
    char* W3q = (char*)d_ws + 2359296;

    pack_kernel<128><<<16384 / 256, 256, 0, stream>>>(W0, W0p, 16384);
    pack8_kernel<<<65536 / 256, 256, 0, stream>>>(W1, W1q, 65536);
    pack8_kernel<<<65536 / 256, 256, 0, stream>>>(W2, W2q, 65536);
    pack3q_kernel<<<8192 / 256, 256, 0, stream>>>(W3, W3q, 8192);

    node_kernel<<<NBLK, NTHREADS, 0, stream>>>(y0, tarr, W_aug, b_aug,
                                               b0, b1, b2, b3,
                                               W0p, W1q, W2q, W3q,
                                               (float*)d_out);
}